// Round 4
// baseline (176.303 us; speedup 1.0000x reference)
//
#include <hip/hip_runtime.h>
#include <stdint.h>

typedef unsigned short u16;
typedef __bf16 bf16_t;
typedef bf16_t bf16x8 __attribute__((ext_vector_type(8)));
typedef float f32x4 __attribute__((ext_vector_type(4)));

static constexpr int P = 65536;  // H*W; D = C = 256

__device__ __forceinline__ float bfbits2f(uint32_t b) {
    union { uint32_t i; float f; } u; u.i = b << 16; return u.f;
}
__device__ __forceinline__ u16 f2bf(float f) {
    union { float f; uint32_t i; } u; u.f = f;
    uint32_t x = u.i + 0x7FFFu + ((u.i >> 16) & 1u);   // RNE
    return (u16)(x >> 16);
}
__device__ __forceinline__ uint32_t pack2(float a, float b) {
    return (uint32_t)f2bf(a) | ((uint32_t)f2bf(b) << 16);
}

// Runtime input-dtype sniff (insurance; verdict on this harness: f32).
__device__ __forceinline__ int detect_bf16_input(const void* Xg) {
    const uint32_t* Xu = (const uint32_t*)Xg;
    const int lane = (int)(threadIdx.x & 63);
    const uint32_t v = Xu[(size_t)lane * 131071u];
    const uint32_t e = (v >> 7) & 0xFFu;
    unsigned long long m = __ballot(e >= 96u && e <= 135u);
    return __popcll(m) >= 40;
}

// Kernel 1: rs[c] = scale[c]*5/max(||w_c||,1e-8)  AND  W -> bf16 row image.
__global__ __launch_bounds__(64) void coshead_prep(
    const void* __restrict__ Xg, const void* __restrict__ Wg,
    const void* __restrict__ Sg, float* __restrict__ rs_ws,
    u16* __restrict__ wbf)
{
    const int c    = (int)blockIdx.x;
    const int lane = (int)threadIdx.x;
    const int bf   = detect_bf16_input(Xg);
    float s;
    uint2 packed;
    if (bf) {
        const uint2 v = *(const uint2*)((const u16*)Wg + (size_t)c * 256 + lane * 4);
        const float a = bfbits2f(v.x & 0xFFFFu), b = bfbits2f(v.x >> 16);
        const float d = bfbits2f(v.y & 0xFFFFu), e = bfbits2f(v.y >> 16);
        s = a * a + b * b + d * d + e * e;
        packed = v;
    } else {
        const f32x4 v = *(const f32x4*)((const float*)Wg + (size_t)c * 256 + lane * 4);
        s = v[0] * v[0] + v[1] * v[1] + v[2] * v[2] + v[3] * v[3];
        packed.x = pack2(v[0], v[1]);
        packed.y = pack2(v[2], v[3]);
    }
    *(uint2*)(wbf + (size_t)c * 256 + lane * 4) = packed;
    s += __shfl_xor(s, 1);  s += __shfl_xor(s, 2);  s += __shfl_xor(s, 4);
    s += __shfl_xor(s, 8);  s += __shfl_xor(s, 16); s += __shfl_xor(s, 32);
    if (lane == 0) {
        const float sc = bf ? bfbits2f((uint32_t)((const u16*)Sg)[c])
                            : ((const float*)Sg)[c];
        rs_ws[c] = sc * 5.0f / fmaxf(sqrtf(s), 1e-8f);
    }
}

// Kernel 2: out[c,p] = (W@X)[c,p] * rs[c] / max(||x_p||,1e-8), f32 out.
// Round-0 skeleton (2 barriers/kc) with the two measured fixes:
//  - sA via global_load_lds from the bf16 W image (no conversion VALU, no
//    staging regs; per-lane pre-swizzled SOURCE, linear LDS dest).
//  - NO cross-barrier register carry (rounds 1-3 lesson: the rA-rD carry
//    spills ~80 B/thread of scratch -> +20..100 MB of HBM traffic).
//  - Grid 512, 2 adjacent pixel-tiles per block: exactly 2 resident
//    blocks/CU, uniform machine load, zero 4th-block tail.
__global__ __launch_bounds__(256, 3) void coshead_gemm(
    const void* __restrict__ Xg_, const u16* __restrict__ Wbf,
    const float* __restrict__ rs_ws, float* __restrict__ Og)
{
    __shared__ char smem_[32768 + 8192];
    char* sA = smem_;            // [256 rows][8 slots x 16 B]; slot s holds granule s^(row&7)
    char* sB = smem_ + 32768;    // [64 pix][8 granules x 16 B], swizzled

    const int t  = (int)threadIdx.x;
    const int l  = t & 63;
    const int w  = t >> 6;
    const int bf = detect_bf16_input(Xg_);

    const int g    = t & 7;      // pixel octet
    const int r    = t >> 3;     // k-pair row 0..31
    const int m16  = l & 15;
    const int quad = l >> 4;

    // sA staging map: call j covers rows 32j + 8w .. +7 (1 KB, lane-linear dest).
    // lane l -> row_local = l>>3, slot = l&7; source granule = slot ^ (row&7),
    // and row&7 == l>>3, so the swizzle is a per-lane constant.
    const int lrow = l >> 3;
    const int gsl  = (l & 7) ^ lrow;
    const u16* wsrc = Wbf + ((size_t)(w * 8 + lrow) << 8) + gsl * 8;
    char* ldsA = sA + w * 1024;   // wave-uniform; + j*4096 per call

    const int pbase = (int)blockIdx.x * 128;

    for (int tile = 0; tile < 2; ++tile) {
        const int p0 = pbase + tile * 64;

        float ssq[8];
#pragma unroll
        for (int j = 0; j < 8; ++j) ssq[j] = 0.f;
        f32x4 acc[4][4];
#pragma unroll
        for (int a = 0; a < 4; ++a)
#pragma unroll
            for (int b = 0; b < 4; ++b)
#pragma unroll
                for (int i = 0; i < 4; ++i) acc[a][b][i] = 0.f;

        for (int kc = 0; kc < 4; ++kc) {
            // ---- A: async-stage 32 KB for this kc; drains at the leading
            // barrier, latency overlapped by the B staging below. ----
#pragma unroll
            for (int j = 0; j < 8; ++j) {
                __builtin_amdgcn_global_load_lds(
                    (const __attribute__((address_space(1))) void*)(wsrc + j * 8192 + kc * 64),
                    (__attribute__((address_space(3))) void*)(ldsA + j * 4096),
                    16, 0, 0);
            }

            if (bf) {
                // ---- insurance path: bf16 input ----
                const u16* xp = (const u16*)Xg_ + (size_t)(2 * r + kc * 64) * P + p0 + g * 8;
                const uint4 v0 = *(const uint4*)xp;
                const uint4 v1 = *(const uint4*)(xp + P);
                const uint32_t e0[4] = {v0.x, v0.y, v0.z, v0.w};
                const uint32_t e1[4] = {v1.x, v1.y, v1.z, v1.w};
#pragma unroll
                for (int d = 0; d < 4; ++d) {
                    const float f00 = bfbits2f(e0[d] & 0xFFFFu), f01 = bfbits2f(e0[d] >> 16);
                    const float f10 = bfbits2f(e1[d] & 0xFFFFu), f11 = bfbits2f(e1[d] >> 16);
                    ssq[2 * d]     += f00 * f00 + f10 * f10;
                    ssq[2 * d + 1] += f01 * f01 + f11 * f11;
                    const uint32_t d0 = (e0[d] & 0xFFFFu) | (e1[d] << 16);
                    const uint32_t d1 = (e0[d] >> 16) | (e1[d] & 0xFFFF0000u);
                    const int pj0 = g * 8 + 2 * d, pj1 = pj0 + 1;
                    *(uint32_t*)(sB + pj0 * 128 + (((r >> 2) ^ (pj0 & 7) ^ g) * 16) + (r & 3) * 4) = d0;
                    *(uint32_t*)(sB + pj1 * 128 + (((r >> 2) ^ (pj1 & 7) ^ g) * 16) + (r & 3) * 4) = d1;
                }
            } else {
                // ---- f32 path: load in-loop, consume immediately (no carry) ----
                const float* xp = (const float*)Xg_ + (size_t)(2 * r + kc * 64) * P + p0 + g * 8;
                const f32x4 c0  = *(const f32x4*)xp;
                const f32x4 c1  = *(const f32x4*)(xp + 4);
                const f32x4 d0v = *(const f32x4*)(xp + P);
                const f32x4 d1v = *(const f32x4*)(xp + P + 4);
                const float f0[8] = {c0[0], c0[1], c0[2], c0[3], c1[0], c1[1], c1[2], c1[3]};
                const float f1[8] = {d0v[0], d0v[1], d0v[2], d0v[3], d1v[0], d1v[1], d1v[2], d1v[3]};
#pragma unroll
                for (int j = 0; j < 8; ++j) {
                    ssq[j] += f0[j] * f0[j] + f1[j] * f1[j];
                    const int pix = g * 8 + j;
                    *(uint32_t*)(sB + pix * 128 + (((r >> 2) ^ (pix & 7) ^ g) * 16) + (r & 3) * 4) =
                        pack2(f0[j], f1[j]);
                }
            }
            __syncthreads();   // sA gloads complete + sB writes visible

            // ---- MFMA: 2 K=32 steps; wave tile 64 classes x 64 pixels ----
#pragma unroll
            for (int kk = 0; kk < 2; ++kk) {
                bf16x8 af[4], bfr[4];
#pragma unroll
                for (int tm = 0; tm < 4; ++tm) {
                    const int row = w * 64 + tm * 16 + m16;
                    af[tm] = *(const bf16x8*)(sA + row * 128 + (((kk * 4 + quad) ^ (row & 7)) * 16));
                }
#pragma unroll
                for (int tn = 0; tn < 4; ++tn) {
                    const int pix = tn * 16 + m16;
                    bfr[tn] = *(const bf16x8*)(sB + pix * 128 +
                               (((kk * 4 + quad) ^ (pix & 7) ^ (pix >> 3)) * 16));
                }
#pragma unroll
                for (int tm = 0; tm < 4; ++tm)
#pragma unroll
                    for (int tn = 0; tn < 4; ++tn)
                        acc[tm][tn] = __builtin_amdgcn_mfma_f32_16x16x32_bf16(
                            af[tm], bfr[tn], acc[tm][tn], 0, 0, 0);
            }
            __syncthreads();   // protects sA/sB rewrite
        }

        // ---- epilogue: x-norms via LDS transpose-reduce (reuse smem_) ----
        float* xs   = (float*)sA;    // [32][64] partial ssq
        float* xinv = (float*)sB;    // [64]
#pragma unroll
        for (int j = 0; j < 8; ++j) xs[r * 64 + g * 8 + j] = ssq[j];
        __syncthreads();
        if (t < 64) {
            float sx = 0.f;
#pragma unroll
            for (int rr = 0; rr < 32; ++rr) sx += xs[rr * 64 + t];
            xinv[t] = 1.0f / fmaxf(sqrtf(sx), 1e-8f);
        }
        __syncthreads();

        // ---- scaled f32 store. class = w*64+tm*16+quad*4+i ; pixel = p0+tn*16+m16 ----
        float inv4[4];
#pragma unroll
        for (int tn = 0; tn < 4; ++tn) inv4[tn] = xinv[tn * 16 + m16];
#pragma unroll
        for (int tm = 0; tm < 4; ++tm) {
            const int cbase = w * 64 + tm * 16 + quad * 4;
            const f32x4 rs4 = *(const f32x4*)(rs_ws + cbase);
#pragma unroll
            for (int tn = 0; tn < 4; ++tn) {
#pragma unroll
                for (int i = 0; i < 4; ++i) {
                    Og[(size_t)(cbase + i) * P + p0 + tn * 16 + m16] =
                        acc[tm][tn][i] * rs4[i] * inv4[tn];
                }
            }
        }
        __syncthreads();   // xinv reads done before next tile's staging
    }
}

extern "C" void kernel_launch(void* const* d_in, const int* in_sizes, int n_in,
                              void* d_out, int out_size, void* d_ws, size_t ws_size,
                              hipStream_t stream) {
    (void)out_size; (void)ws_size;
    const void* X = d_in[0];
    const void* W = d_in[1];
    const void* S = d_in[2];
    for (int i = 0; i < n_in; ++i) {
        if (in_sizes[i] == 256 * 65536) X = d_in[i];
        else if (in_sizes[i] == 256 * 256) W = d_in[i];
        else if (in_sizes[i] == 256)      S = d_in[i];
    }
    float* rs  = (float*)d_ws;
    u16*   wbf = (u16*)((char*)d_ws + 1024);   // 128 KB bf16 W image
    coshead_prep<<<dim3(256), dim3(64), 0, stream>>>(X, W, S, rs, wbf);
    coshead_gemm<<<dim3(512), dim3(256), 0, stream>>>(X, wbf, rs, (float*)d_out);
}

// Round 5
// 136.885 us; speedup vs baseline: 1.2880x; 1.2880x over previous
//
#include <hip/hip_runtime.h>
#include <stdint.h>

typedef unsigned short u16;
typedef __bf16 bf16_t;
typedef bf16_t bf16x8 __attribute__((ext_vector_type(8)));
typedef float f32x4 __attribute__((ext_vector_type(4)));

static constexpr int P = 65536;  // H*W; D = C = 256

__device__ __forceinline__ float bfbits2f(uint32_t b) {
    union { uint32_t i; float f; } u; u.i = b << 16; return u.f;
}
__device__ __forceinline__ u16 f2bf(float f) {
    union { float f; uint32_t i; } u; u.f = f;
    uint32_t x = u.i + 0x7FFFu + ((u.i >> 16) & 1u);   // RNE
    return (u16)(x >> 16);
}
__device__ __forceinline__ uint32_t pack2(float a, float b) {
    return (uint32_t)f2bf(a) | ((uint32_t)f2bf(b) << 16);
}

// Runtime input-dtype sniff (insurance; verdict on this harness: f32).
__device__ __forceinline__ int detect_bf16_input(const void* Xg) {
    const uint32_t* Xu = (const uint32_t*)Xg;
    const int lane = (int)(threadIdx.x & 63);
    const uint32_t v = Xu[(size_t)lane * 131071u];
    const uint32_t e = (v >> 7) & 0xFFu;
    unsigned long long m = __ballot(e >= 96u && e <= 135u);
    return __popcll(m) >= 40;
}

// Kernel 1: rs[c] = scale[c]*5/max(||w_c||,1e-8)  AND  W -> bf16 row image.
__global__ __launch_bounds__(64) void coshead_prep(
    const void* __restrict__ Xg, const void* __restrict__ Wg,
    const void* __restrict__ Sg, float* __restrict__ rs_ws,
    u16* __restrict__ wbf)
{
    const int c    = (int)blockIdx.x;
    const int lane = (int)threadIdx.x;
    const int bf   = detect_bf16_input(Xg);
    float s;
    uint2 packed;
    if (bf) {
        const uint2 v = *(const uint2*)((const u16*)Wg + (size_t)c * 256 + lane * 4);
        const float a = bfbits2f(v.x & 0xFFFFu), b = bfbits2f(v.x >> 16);
        const float d = bfbits2f(v.y & 0xFFFFu), e = bfbits2f(v.y >> 16);
        s = a * a + b * b + d * d + e * e;
        packed = v;
    } else {
        const f32x4 v = *(const f32x4*)((const float*)Wg + (size_t)c * 256 + lane * 4);
        s = v[0] * v[0] + v[1] * v[1] + v[2] * v[2] + v[3] * v[3];
        packed.x = pack2(v[0], v[1]);
        packed.y = pack2(v[2], v[3]);
    }
    *(uint2*)(wbf + (size_t)c * 256 + lane * 4) = packed;
    s += __shfl_xor(s, 1);  s += __shfl_xor(s, 2);  s += __shfl_xor(s, 4);
    s += __shfl_xor(s, 8);  s += __shfl_xor(s, 16); s += __shfl_xor(s, 32);
    if (lane == 0) {
        const float sc = bf ? bfbits2f((uint32_t)((const u16*)Sg)[c])
                            : ((const float*)Sg)[c];
        rs_ws[c] = sc * 5.0f / fmaxf(sqrtf(s), 1e-8f);
    }
}

// Kernel 1b: X (f32 or bf16) -> XB tile image + xinv.
// XB[b] = 32 KB: [kc=4][pix=64][128 B of k-linear bf16 (k-pair words)],
// i.e. exactly the bytes the gemm's sB held per (block, kc), UN-swizzled.
// Staging into LDS uses the round-0-proven swizzled code VERBATIM (incl. ssq
// order -> xinv bit-identical); readout un-swizzles and writes coalesced.
__global__ __launch_bounds__(256) void coshead_xprep(
    const void* __restrict__ Xg_, u16* __restrict__ XB,
    float* __restrict__ xinv_g)
{
    __shared__ char sB[32768];
    const int t  = (int)threadIdx.x;
    const int g  = t & 7;      // pixel octet
    const int r  = t >> 3;     // k-pair row 0..31
    const int p0 = (int)blockIdx.x * 64;
    const int bf = detect_bf16_input(Xg_);

    float ssq[8];
#pragma unroll
    for (int j = 0; j < 8; ++j) ssq[j] = 0.f;

    for (int kc = 0; kc < 4; ++kc) {
        char* sBk = sB + kc * 8192;
        if (bf) {
            const u16* xp = (const u16*)Xg_ + (size_t)(2 * r + kc * 64) * P + p0 + g * 8;
            const uint4 v0 = *(const uint4*)xp;
            const uint4 v1 = *(const uint4*)(xp + P);
            const uint32_t e0[4] = {v0.x, v0.y, v0.z, v0.w};
            const uint32_t e1[4] = {v1.x, v1.y, v1.z, v1.w};
#pragma unroll
            for (int d = 0; d < 4; ++d) {
                const float f00 = bfbits2f(e0[d] & 0xFFFFu), f01 = bfbits2f(e0[d] >> 16);
                const float f10 = bfbits2f(e1[d] & 0xFFFFu), f11 = bfbits2f(e1[d] >> 16);
                ssq[2 * d]     += f00 * f00 + f10 * f10;
                ssq[2 * d + 1] += f01 * f01 + f11 * f11;
                const uint32_t d0 = (e0[d] & 0xFFFFu) | (e1[d] << 16);
                const uint32_t d1 = (e0[d] >> 16) | (e1[d] & 0xFFFF0000u);
                const int pj0 = g * 8 + 2 * d, pj1 = pj0 + 1;
                *(uint32_t*)(sBk + pj0 * 128 + (((r >> 2) ^ (pj0 & 7) ^ g) * 16) + (r & 3) * 4) = d0;
                *(uint32_t*)(sBk + pj1 * 128 + (((r >> 2) ^ (pj1 & 7) ^ g) * 16) + (r & 3) * 4) = d1;
            }
        } else {
            const float* xp = (const float*)Xg_ + (size_t)(2 * r + kc * 64) * P + p0 + g * 8;
            const f32x4 c0  = *(const f32x4*)xp;
            const f32x4 c1  = *(const f32x4*)(xp + 4);
            const f32x4 d0v = *(const f32x4*)(xp + P);
            const f32x4 d1v = *(const f32x4*)(xp + P + 4);
            const float f0[8] = {c0[0], c0[1], c0[2], c0[3], c1[0], c1[1], c1[2], c1[3]};
            const float f1[8] = {d0v[0], d0v[1], d0v[2], d0v[3], d1v[0], d1v[1], d1v[2], d1v[3]};
#pragma unroll
            for (int j = 0; j < 8; ++j) {
                ssq[j] += f0[j] * f0[j] + f1[j] * f1[j];
                const int pix = g * 8 + j;
                *(uint32_t*)(sBk + pix * 128 + (((r >> 2) ^ (pix & 7) ^ g) * 16) + (r & 3) * 4) =
                    pack2(f0[j], f1[j]);
            }
        }
    }
    __syncthreads();

    // ---- un-swizzling readout: 32 KB -> XB[b], fully coalesced stores ----
    {
        char* dst = (char*)XB + (size_t)blockIdx.x * 32768;
#pragma unroll
        for (int s = 0; s < 8; ++s) {
            const int o    = s * 4096 + t * 16;          // linear dest offset
            const int kc_o = o >> 13;
            const int pix  = (o & 8191) >> 7;
            const int gd   = t & 7;                       // == (o>>4)&7
            const int slot = gd ^ (pix & 7) ^ (pix >> 3); // where gd lives in LDS
            *(uint4*)(dst + o) =
                *(const uint4*)(sB + kc_o * 8192 + pix * 128 + slot * 16);
        }
    }
    __syncthreads();

    // ---- x-norms: identical reduce to round 0 -> bit-identical xinv ----
    float* xs = (float*)sB;   // [32][64]
#pragma unroll
    for (int j = 0; j < 8; ++j) xs[r * 64 + g * 8 + j] = ssq[j];
    __syncthreads();
    if (t < 64) {
        float sx = 0.f;
#pragma unroll
        for (int rr = 0; rr < 32; ++rr) sx += xs[rr * 64 + t];
        xinv_g[p0 + t] = 1.0f / fmaxf(sqrtf(sx), 1e-8f);
    }
}

// Kernel 2: pure-DMA GEMM. A and B both staged by global_load_lds (no f32
// loads, no conversion VALU, no ssq). Swizzle baked into per-lane SOURCE
// addresses; LDS dests linear; MFMA read formulas identical to the proven
// kernel. (256,4) + grid 1024: exactly 4 blocks/CU (LDS 40KB x 4 = 160KB),
// zero tail. Live set ~110 regs incl. 64 acc -> fits the 128 cap.
__global__ __launch_bounds__(256, 4) void coshead_gemm2(
    const u16* __restrict__ XB, const u16* __restrict__ Wbf,
    const float* __restrict__ rs_ws, const float* __restrict__ xinv_g,
    float* __restrict__ Og)
{
    __shared__ char smem_[32768 + 8192];
    char* sA = smem_;            // [256 rows][8 slots x 16 B]; slot s holds granule s^(row&7)
    char* sB = smem_ + 32768;    // [64 pix][8 slots x 16 B];   slot s holds granule s^(pix&7)^(pix>>3)

    const int t    = (int)threadIdx.x;
    const int l    = t & 63;
    const int w    = t >> 6;
    const int m16  = l & 15;
    const int quad = l >> 4;
    const int p0   = (int)blockIdx.x * 64;

    // A source (proven round-3 mapping): call j covers rows j*32 + w*8 .. +7.
    const int lrow = l >> 3;
    const int gslA = (l & 7) ^ lrow;
    const u16* wsrc = Wbf + ((size_t)(w * 8 + lrow) << 8) + gslA * 8;
    char* ldsA = sA + w * 1024;   // wave-uniform dest; +j*4096 per call

    // B source: call c = w*2+jj covers pixels c*8..c*8+7 (1 KB each).
    // lane l -> pix = c*8 + (l>>3), slot = l&7; data granule gd = slot^(l>>3)^c.
    const u16* xbb = XB + (size_t)blockIdx.x * 16384;

    f32x4 acc[4][4];
#pragma unroll
    for (int a = 0; a < 4; ++a)
#pragma unroll
        for (int b = 0; b < 4; ++b)
#pragma unroll
            for (int i = 0; i < 4; ++i) acc[a][b][i] = 0.f;

    for (int kc = 0; kc < 4; ++kc) {
        // ---- A: 8 x 1 KB from bf16 W image (L2-resident) ----
#pragma unroll
        for (int j = 0; j < 8; ++j) {
            __builtin_amdgcn_global_load_lds(
                (const __attribute__((address_space(1))) void*)(wsrc + j * 8192 + kc * 64),
                (__attribute__((address_space(3))) void*)(ldsA + j * 4096),
                16, 0, 0);
        }
        // ---- B: 2 x 1 KB from XB tile image (L3-resident) ----
#pragma unroll
        for (int jj = 0; jj < 2; ++jj) {
            const int c   = w * 2 + jj;
            const int pix = c * 8 + lrow;
            const int gd  = (l & 7) ^ lrow ^ c;
            __builtin_amdgcn_global_load_lds(
                (const __attribute__((address_space(1))) void*)(xbb + kc * 4096 + pix * 64 + gd * 8),
                (__attribute__((address_space(3))) void*)(sB + c * 1024),
                16, 0, 0);
        }
        __syncthreads();   // all gloads drained, tiles visible

        // ---- MFMA: 2 K=32 steps; wave tile 64 classes x 64 pixels ----
#pragma unroll
        for (int kk = 0; kk < 2; ++kk) {
            bf16x8 af[4], bfr[4];
#pragma unroll
            for (int tm = 0; tm < 4; ++tm) {
                const int row = w * 64 + tm * 16 + m16;
                af[tm] = *(const bf16x8*)(sA + row * 128 + (((kk * 4 + quad) ^ (row & 7)) * 16));
            }
#pragma unroll
            for (int tn = 0; tn < 4; ++tn) {
                const int pix = tn * 16 + m16;
                bfr[tn] = *(const bf16x8*)(sB + pix * 128 +
                           (((kk * 4 + quad) ^ (pix & 7) ^ (pix >> 3)) * 16));
            }
#pragma unroll
            for (int tm = 0; tm < 4; ++tm)
#pragma unroll
                for (int tn = 0; tn < 4; ++tn)
                    acc[tm][tn] = __builtin_amdgcn_mfma_f32_16x16x32_bf16(
                        af[tm], bfr[tn], acc[tm][tn], 0, 0, 0);
        }
        __syncthreads();   // protect rewrite next kc
    }

    // ---- epilogue: xinv from global (no LDS reduce needed) ----
    float inv4[4];
#pragma unroll
    for (int tn = 0; tn < 4; ++tn) inv4[tn] = xinv_g[p0 + tn * 16 + m16];
#pragma unroll
    for (int tm = 0; tm < 4; ++tm) {
        const int cbase = w * 64 + tm * 16 + quad * 4;
        const f32x4 rs4 = *(const f32x4*)(rs_ws + cbase);
#pragma unroll
        for (int tn = 0; tn < 4; ++tn) {
#pragma unroll
            for (int i = 0; i < 4; ++i) {
                Og[(size_t)(cbase + i) * P + p0 + tn * 16 + m16] =
                    acc[tm][tn][i] * rs4[i] * inv4[tn];
            }
        }
    }
}

// Fallback (round-3 gemm, harness-proven): used if workspace is too small
// for the 32 MB XB image.
__global__ __launch_bounds__(256, 3) void coshead_gemm_fb(
    const void* __restrict__ Xg_, const u16* __restrict__ Wbf,
    const float* __restrict__ rs_ws, float* __restrict__ Og)
{
    __shared__ char smem_[32768 + 8192];
    char* sA = smem_;
    char* sB = smem_ + 32768;

    const int t  = (int)threadIdx.x;
    const int l  = t & 63;
    const int w  = t >> 6;
    const int p0 = (int)blockIdx.x * 64;
    const int bf = detect_bf16_input(Xg_);

    const int g    = t & 7;
    const int r    = t >> 3;
    const int m16  = l & 15;
    const int quad = l >> 4;

    const int lrow = l >> 3;
    const int gsl  = (l & 7) ^ lrow;
    const u16* wsrc = Wbf + ((size_t)(w * 8 + lrow) << 8) + gsl * 8;
    char* ldsA = sA + w * 1024;

    float ssq[8];
#pragma unroll
    for (int j = 0; j < 8; ++j) ssq[j] = 0.f;
    f32x4 acc[4][4];
#pragma unroll
    for (int a = 0; a < 4; ++a)
#pragma unroll
        for (int b = 0; b < 4; ++b)
#pragma unroll
            for (int i = 0; i < 4; ++i) acc[a][b][i] = 0.f;

    for (int kc = 0; kc < 4; ++kc) {
#pragma unroll
        for (int j = 0; j < 8; ++j) {
            __builtin_amdgcn_global_load_lds(
                (const __attribute__((address_space(1))) void*)(wsrc + j * 8192 + kc * 64),
                (__attribute__((address_space(3))) void*)(ldsA + j * 4096),
                16, 0, 0);
        }
        if (bf) {
            const u16* xp = (const u16*)Xg_ + (size_t)(2 * r + kc * 64) * P + p0 + g * 8;
            const uint4 v0 = *(const uint4*)xp;
            const uint4 v1 = *(const uint4*)(xp + P);
            const uint32_t e0[4] = {v0.x, v0.y, v0.z, v0.w};
            const uint32_t e1[4] = {v1.x, v1.y, v1.z, v1.w};
#pragma unroll
            for (int d = 0; d < 4; ++d) {
                const float f00 = bfbits2f(e0[d] & 0xFFFFu), f01 = bfbits2f(e0[d] >> 16);
                const float f10 = bfbits2f(e1[d] & 0xFFFFu), f11 = bfbits2f(e1[d] >> 16);
                ssq[2 * d]     += f00 * f00 + f10 * f10;
                ssq[2 * d + 1] += f01 * f01 + f11 * f11;
                const uint32_t d0 = (e0[d] & 0xFFFFu) | (e1[d] << 16);
                const uint32_t d1 = (e0[d] >> 16) | (e1[d] & 0xFFFF0000u);
                const int pj0 = g * 8 + 2 * d, pj1 = pj0 + 1;
                *(uint32_t*)(sB + pj0 * 128 + (((r >> 2) ^ (pj0 & 7) ^ g) * 16) + (r & 3) * 4) = d0;
                *(uint32_t*)(sB + pj1 * 128 + (((r >> 2) ^ (pj1 & 7) ^ g) * 16) + (r & 3) * 4) = d1;
            }
        } else {
            const float* xp = (const float*)Xg_ + (size_t)(2 * r + kc * 64) * P + p0 + g * 8;
            const f32x4 c0  = *(const f32x4*)xp;
            const f32x4 c1  = *(const f32x4*)(xp + 4);
            const f32x4 d0v = *(const f32x4*)(xp + P);
            const f32x4 d1v = *(const f32x4*)(xp + P + 4);
            const float f0[8] = {c0[0], c0[1], c0[2], c0[3], c1[0], c1[1], c1[2], c1[3]};
            const float f1[8] = {d0v[0], d0v[1], d0v[2], d0v[3], d1v[0], d1v[1], d1v[2], d1v[3]};
#pragma unroll
            for (int j = 0; j < 8; ++j) {
                ssq[j] += f0[j] * f0[j] + f1[j] * f1[j];
                const int pix = g * 8 + j;
                *(uint32_t*)(sB + pix * 128 + (((r >> 2) ^ (pix & 7) ^ g) * 16) + (r & 3) * 4) =
                    pack2(f0[j], f1[j]);
            }
        }
        __syncthreads();
#pragma unroll
        for (int kk = 0; kk < 2; ++kk) {
            bf16x8 af[4], bfr[4];
#pragma unroll
            for (int tm = 0; tm < 4; ++tm) {
                const int row = w * 64 + tm * 16 + m16;
                af[tm] = *(const bf16x8*)(sA + row * 128 + (((kk * 4 + quad) ^ (row & 7)) * 16));
            }
#pragma unroll
            for (int tn = 0; tn < 4; ++tn) {
                const int pix = tn * 16 + m16;
                bfr[tn] = *(const bf16x8*)(sB + pix * 128 +
                           (((kk * 4 + quad) ^ (pix & 7) ^ (pix >> 3)) * 16));
            }
#pragma unroll
            for (int tm = 0; tm < 4; ++tm)
#pragma unroll
                for (int tn = 0; tn < 4; ++tn)
                    acc[tm][tn] = __builtin_amdgcn_mfma_f32_16x16x32_bf16(
                        af[tm], bfr[tn], acc[tm][tn], 0, 0, 0);
        }
        __syncthreads();
    }

    float* xs   = (float*)sA;
    float* xinv = (float*)sB;
#pragma unroll
    for (int j = 0; j < 8; ++j) xs[r * 64 + g * 8 + j] = ssq[j];
    __syncthreads();
    if (t < 64) {
        float sx = 0.f;
#pragma unroll
        for (int rr = 0; rr < 32; ++rr) sx += xs[rr * 64 + t];
        xinv[t] = 1.0f / fmaxf(sqrtf(sx), 1e-8f);
    }
    __syncthreads();

    float inv4[4];
#pragma unroll
    for (int tn = 0; tn < 4; ++tn) inv4[tn] = xinv[tn * 16 + m16];
#pragma unroll
    for (int tm = 0; tm < 4; ++tm) {
        const int cbase = w * 64 + tm * 16 + quad * 4;
        const f32x4 rs4 = *(const f32x4*)(rs_ws + cbase);
#pragma unroll
        for (int tn = 0; tn < 4; ++tn) {
#pragma unroll
            for (int i = 0; i < 4; ++i) {
                Og[(size_t)(cbase + i) * P + p0 + tn * 16 + m16] =
                    acc[tm][tn][i] * rs4[i] * inv4[tn];
            }
        }
    }
}

extern "C" void kernel_launch(void* const* d_in, const int* in_sizes, int n_in,
                              void* d_out, int out_size, void* d_ws, size_t ws_size,
                              hipStream_t stream) {
    (void)out_size;
    const void* X = d_in[0];
    const void* W = d_in[1];
    const void* S = d_in[2];
    for (int i = 0; i < n_in; ++i) {
        if (in_sizes[i] == 256 * 65536) X = d_in[i];
        else if (in_sizes[i] == 256 * 256) W = d_in[i];
        else if (in_sizes[i] == 256)      S = d_in[i];
    }
    float* rs  = (float*)d_ws;
    u16*   wbf = (u16*)((char*)d_ws + 1024);        // 128 KB bf16 W image
    const size_t XINV_OFF = 132096;                 // 256 KB
    const size_t XB_OFF   = 394240;                 // 32 MB
    const size_t NEED     = XB_OFF + (size_t)1024 * 32768;

    coshead_prep<<<dim3(256), dim3(64), 0, stream>>>(X, W, S, rs, wbf);
    if (ws_size >= NEED) {
        float* xinv = (float*)((char*)d_ws + XINV_OFF);
        u16*   XBp  = (u16*)((char*)d_ws + XB_OFF);
        coshead_xprep<<<dim3(1024), dim3(256), 0, stream>>>(X, XBp, xinv);
        coshead_gemm2<<<dim3(1024), dim3(256), 0, stream>>>(XBp, wbf, rs, xinv, (float*)d_out);
    } else {
        coshead_gemm_fb<<<dim3(1024), dim3(256), 0, stream>>>(X, wbf, rs, (float*)d_out);
    }
}

// Round 7
// 135.174 us; speedup vs baseline: 1.3043x; 1.0127x over previous
//
#include <hip/hip_runtime.h>
#include <stdint.h>

typedef unsigned short u16;
typedef __bf16 bf16_t;
typedef bf16_t bf16x8 __attribute__((ext_vector_type(8)));
typedef float f32x4 __attribute__((ext_vector_type(4)));

static constexpr int P = 65536;  // H*W; D = C = 256

__device__ __forceinline__ float bfbits2f(uint32_t b) {
    union { uint32_t i; float f; } u; u.i = b << 16; return u.f;
}
__device__ __forceinline__ u16 f2bf(float f) {
    union { float f; uint32_t i; } u; u.f = f;
    uint32_t x = u.i + 0x7FFFu + ((u.i >> 16) & 1u);   // RNE
    return (u16)(x >> 16);
}
__device__ __forceinline__ uint32_t pack2(float a, float b) {
    return (uint32_t)f2bf(a) | ((uint32_t)f2bf(b) << 16);
}

// Runtime input-dtype sniff (insurance; verdict on this harness: f32).
__device__ __forceinline__ int detect_bf16_input(const void* Xg) {
    const uint32_t* Xu = (const uint32_t*)Xg;
    const int lane = (int)(threadIdx.x & 63);
    const uint32_t v = Xu[(size_t)lane * 131071u];
    const uint32_t e = (v >> 7) & 0xFFu;
    unsigned long long m = __ballot(e >= 96u && e <= 135u);
    return __popcll(m) >= 40;
}

// Kernel 1: rs[c] = scale[c]*5/max(||w_c||,1e-8)  AND  W -> bf16 row image.
__global__ __launch_bounds__(64) void coshead_prep(
    const void* __restrict__ Xg, const void* __restrict__ Wg,
    const void* __restrict__ Sg, float* __restrict__ rs_ws,
    u16* __restrict__ wbf)
{
    const int c    = (int)blockIdx.x;
    const int lane = (int)threadIdx.x;
    const int bf   = detect_bf16_input(Xg);
    float s;
    uint2 packed;
    if (bf) {
        const uint2 v = *(const uint2*)((const u16*)Wg + (size_t)c * 256 + lane * 4);
        const float a = bfbits2f(v.x & 0xFFFFu), b = bfbits2f(v.x >> 16);
        const float d = bfbits2f(v.y & 0xFFFFu), e = bfbits2f(v.y >> 16);
        s = a * a + b * b + d * d + e * e;
        packed = v;
    } else {
        const f32x4 v = *(const f32x4*)((const float*)Wg + (size_t)c * 256 + lane * 4);
        s = v[0] * v[0] + v[1] * v[1] + v[2] * v[2] + v[3] * v[3];
        packed.x = pack2(v[0], v[1]);
        packed.y = pack2(v[2], v[3]);
    }
    *(uint2*)(wbf + (size_t)c * 256 + lane * 4) = packed;
    s += __shfl_xor(s, 1);  s += __shfl_xor(s, 2);  s += __shfl_xor(s, 4);
    s += __shfl_xor(s, 8);  s += __shfl_xor(s, 16); s += __shfl_xor(s, 32);
    if (lane == 0) {
        const float sc = bf ? bfbits2f((uint32_t)((const u16*)Sg)[c])
                            : ((const float*)Sg)[c];
        rs_ws[c] = sc * 5.0f / fmaxf(sqrtf(s), 1e-8f);
    }
}

// Kernel 2 (fused, barrier-minimal):
//  Phase 1: stream X -> LDS sB for ALL 4 kc (32 KB), fused ssq. NO barriers
//    inside the loop (disjoint LDS addresses per thread) -> compiler keeps
//    many X loads in flight across kc iterations.
//  Barrier #1. Wave 0 computes xinv into LDS (others proceed).
//  Phase 2: barrier-free MFMA. A fragments straight from the L2-resident
//    bf16 W image into registers (round-2-proven mapping); B from read-only
//    LDS. No LDS writes -> no barriers. '#pragma unroll 1' on kc stops the
//    compiler hoisting 32 A-fragments (round-2 spill lesson).
//  Barrier #2, then epilogue (xinv visibility).
// Numerics: same f2bf RNE, same ssq/reduce order, same MFMA accumulation
// order as all passing rounds -> bit-identical output.
__global__ __launch_bounds__(256, 3) void coshead_fused(
    const void* __restrict__ Xg_, const u16* __restrict__ Wbf,
    const float* __restrict__ rs_ws, float* __restrict__ Og)
{
    __shared__ char smem_[32768 + 8192 + 256];
    char*  sB   = smem_;                          // [4 kc][64 pix][8 slots x 16 B] swizzled
    float* xs   = (float*)(smem_ + 32768);        // [32][64] partial ssq
    float* xinv = (float*)(smem_ + 32768 + 8192); // [64]

    const int t  = (int)threadIdx.x;
    const int l  = t & 63;
    const int w  = t >> 6;
    const int p0 = (int)blockIdx.x * 64;
    const int bf = detect_bf16_input(Xg_);

    const int g    = t & 7;      // pixel octet
    const int r    = t >> 3;     // k-pair row 0..31
    const int m16  = l & 15;
    const int quad = l >> 4;

    float ssq[8];
#pragma unroll
    for (int j = 0; j < 8; ++j) ssq[j] = 0.f;

    // ---- Phase 1: stage B for all kc, barrier-free ----
#pragma unroll
    for (int kc = 0; kc < 4; ++kc) {
        char* sBk = sB + kc * 8192;
        if (bf) {
            const u16* xp = (const u16*)Xg_ + (size_t)(2 * r + kc * 64) * P + p0 + g * 8;
            const uint4 v0 = *(const uint4*)xp;
            const uint4 v1 = *(const uint4*)(xp + P);
            const uint32_t e0[4] = {v0.x, v0.y, v0.z, v0.w};
            const uint32_t e1[4] = {v1.x, v1.y, v1.z, v1.w};
#pragma unroll
            for (int d = 0; d < 4; ++d) {
                const float f00 = bfbits2f(e0[d] & 0xFFFFu), f01 = bfbits2f(e0[d] >> 16);
                const float f10 = bfbits2f(e1[d] & 0xFFFFu), f11 = bfbits2f(e1[d] >> 16);
                ssq[2 * d]     += f00 * f00 + f10 * f10;
                ssq[2 * d + 1] += f01 * f01 + f11 * f11;
                const uint32_t d0 = (e0[d] & 0xFFFFu) | (e1[d] << 16);
                const uint32_t d1 = (e0[d] >> 16) | (e1[d] & 0xFFFF0000u);
                const int pj0 = g * 8 + 2 * d, pj1 = pj0 + 1;
                *(uint32_t*)(sBk + pj0 * 128 + (((r >> 2) ^ (pj0 & 7) ^ g) * 16) + (r & 3) * 4) = d0;
                *(uint32_t*)(sBk + pj1 * 128 + (((r >> 2) ^ (pj1 & 7) ^ g) * 16) + (r & 3) * 4) = d1;
            }
        } else {
            const float* xp = (const float*)Xg_ + (size_t)(2 * r + kc * 64) * P + p0 + g * 8;
            const f32x4 c0  = *(const f32x4*)xp;
            const f32x4 c1  = *(const f32x4*)(xp + 4);
            const f32x4 d0v = *(const f32x4*)(xp + P);
            const f32x4 d1v = *(const f32x4*)(xp + P + 4);
            const float f0[8] = {c0[0], c0[1], c0[2], c0[3], c1[0], c1[1], c1[2], c1[3]};
            const float f1[8] = {d0v[0], d0v[1], d0v[2], d0v[3], d1v[0], d1v[1], d1v[2], d1v[3]};
#pragma unroll
            for (int j = 0; j < 8; ++j) {
                ssq[j] += f0[j] * f0[j] + f1[j] * f1[j];
                const int pix = g * 8 + j;
                *(uint32_t*)(sBk + pix * 128 + (((r >> 2) ^ (pix & 7) ^ g) * 16) + (r & 3) * 4) =
                    pack2(f0[j], f1[j]);
            }
        }
    }

    // partial ssq -> xs (separate LDS region), then the ONE staging barrier
#pragma unroll
    for (int j = 0; j < 8; ++j) xs[r * 64 + g * 8 + j] = ssq[j];
    __syncthreads();   // barrier #1: sB + xs visible

    // wave 0 computes xinv; other waves fall straight through to MFMA
    if (t < 64) {
        float sx = 0.f;
#pragma unroll
        for (int rr = 0; rr < 32; ++rr) sx += xs[rr * 64 + t];
        xinv[t] = 1.0f / fmaxf(sqrtf(sx), 1e-8f);
    }

    // ---- Phase 2: barrier-free MFMA; A direct from bf16 W image (L2) ----
    f32x4 acc[4][4];
#pragma unroll
    for (int a = 0; a < 4; ++a)
#pragma unroll
        for (int b = 0; b < 4; ++b)
#pragma unroll
            for (int i = 0; i < 4; ++i) acc[a][b][i] = 0.f;

    const u16* wrow = Wbf + (size_t)(w * 64 + m16) * 256 + quad * 8;

#pragma unroll 1
    for (int kc = 0; kc < 4; ++kc) {
        const u16* wk = wrow + kc * 64;
        const char* sBk = sB + kc * 8192;
#pragma unroll
        for (int kk = 0; kk < 2; ++kk) {
            bf16x8 af[4], bfr[4];
#pragma unroll
            for (int tm = 0; tm < 4; ++tm)
                af[tm] = *(const bf16x8*)(wk + tm * 16 * 256 + kk * 32);
#pragma unroll
            for (int tn = 0; tn < 4; ++tn) {
                const int pix = tn * 16 + m16;
                bfr[tn] = *(const bf16x8*)(sBk + pix * 128 +
                           (((kk * 4 + quad) ^ (pix & 7) ^ (pix >> 3)) * 16));
            }
#pragma unroll
            for (int tm = 0; tm < 4; ++tm)
#pragma unroll
                for (int tn = 0; tn < 4; ++tn)
                    acc[tm][tn] = __builtin_amdgcn_mfma_f32_16x16x32_bf16(
                        af[tm], bfr[tn], acc[tm][tn], 0, 0, 0);
        }
    }

    __syncthreads();   // barrier #2: xinv visible

    // ---- scaled f32 store. class = w*64+tm*16+quad*4+i ; pixel = p0+tn*16+m16 ----
    float inv4[4];
#pragma unroll
    for (int tn = 0; tn < 4; ++tn) inv4[tn] = xinv[tn * 16 + m16];
#pragma unroll
    for (int tm = 0; tm < 4; ++tm) {
        const int cbase = w * 64 + tm * 16 + quad * 4;
        const f32x4 rs4 = *(const f32x4*)(rs_ws + cbase);
#pragma unroll
        for (int tn = 0; tn < 4; ++tn) {
#pragma unroll
            for (int i = 0; i < 4; ++i) {
                Og[(size_t)(cbase + i) * P + p0 + tn * 16 + m16] =
                    acc[tm][tn][i] * rs4[i] * inv4[tn];
            }
        }
    }
}

extern "C" void kernel_launch(void* const* d_in, const int* in_sizes, int n_in,
                              void* d_out, int out_size, void* d_ws, size_t ws_size,
                              hipStream_t stream) {
    (void)out_size; (void)ws_size;
    const void* X = d_in[0];
    const void* W = d_in[1];
    const void* S = d_in[2];
    for (int i = 0; i < n_in; ++i) {
        if (in_sizes[i] == 256 * 65536) X = d_in[i];
        else if (in_sizes[i] == 256 * 256) W = d_in[i];
        else if (in_sizes[i] == 256)      S = d_in[i];
    }
    float* rs  = (float*)d_ws;
    u16*   wbf = (u16*)((char*)d_ws + 1024);   // 128 KB bf16 W image
    coshead_prep<<<dim3(256), dim3(64), 0, stream>>>(X, W, S, rs, wbf);
    coshead_fused<<<dim3(1024), dim3(256), 0, stream>>>(X, wbf, rs, (float*)d_out);
}

// Round 8
// 134.816 us; speedup vs baseline: 1.3077x; 1.0026x over previous
//
#include <hip/hip_runtime.h>
#include <stdint.h>

typedef unsigned short u16;
typedef __bf16 bf16_t;
typedef bf16_t bf16x8 __attribute__((ext_vector_type(8)));
typedef float f32x4 __attribute__((ext_vector_type(4)));

static constexpr int P = 65536;  // H*W; D = C = 256

__device__ __forceinline__ float bfbits2f(uint32_t b) {
    union { uint32_t i; float f; } u; u.i = b << 16; return u.f;
}
__device__ __forceinline__ u16 f2bf(float f) {
    union { float f; uint32_t i; } u; u.f = f;
    uint32_t x = u.i + 0x7FFFu + ((u.i >> 16) & 1u);   // RNE
    return (u16)(x >> 16);
}
__device__ __forceinline__ uint32_t pack2(float a, float b) {
    return (uint32_t)f2bf(a) | ((uint32_t)f2bf(b) << 16);
}

// Runtime input-dtype sniff (insurance; verdict on this harness: f32).
__device__ __forceinline__ int detect_bf16_input(const void* Xg) {
    const uint32_t* Xu = (const uint32_t*)Xg;
    const int lane = (int)(threadIdx.x & 63);
    const uint32_t v = Xu[(size_t)lane * 131071u];
    const uint32_t e = (v >> 7) & 0xFFu;
    unsigned long long m = __ballot(e >= 96u && e <= 135u);
    return __popcll(m) >= 40;
}

// Kernel 1: rs[c] = scale[c]*5/max(||w_c||,1e-8)  AND  W -> bf16 row image.
__global__ __launch_bounds__(64) void coshead_prep(
    const void* __restrict__ Xg, const void* __restrict__ Wg,
    const void* __restrict__ Sg, float* __restrict__ rs_ws,
    u16* __restrict__ wbf)
{
    const int c    = (int)blockIdx.x;
    const int lane = (int)threadIdx.x;
    const int bf   = detect_bf16_input(Xg);
    float s;
    uint2 packed;
    if (bf) {
        const uint2 v = *(const uint2*)((const u16*)Wg + (size_t)c * 256 + lane * 4);
        const float a = bfbits2f(v.x & 0xFFFFu), b = bfbits2f(v.x >> 16);
        const float d = bfbits2f(v.y & 0xFFFFu), e = bfbits2f(v.y >> 16);
        s = a * a + b * b + d * d + e * e;
        packed = v;
    } else {
        const f32x4 v = *(const f32x4*)((const float*)Wg + (size_t)c * 256 + lane * 4);
        s = v[0] * v[0] + v[1] * v[1] + v[2] * v[2] + v[3] * v[3];
        packed.x = pack2(v[0], v[1]);
        packed.y = pack2(v[2], v[3]);
    }
    *(uint2*)(wbf + (size_t)c * 256 + lane * 4) = packed;
    s += __shfl_xor(s, 1);  s += __shfl_xor(s, 2);  s += __shfl_xor(s, 4);
    s += __shfl_xor(s, 8);  s += __shfl_xor(s, 16); s += __shfl_xor(s, 32);
    if (lane == 0) {
        const float sc = bf ? bfbits2f((uint32_t)((const u16*)Sg)[c])
                            : ((const float*)Sg)[c];
        rs_ws[c] = sc * 5.0f / fmaxf(sqrtf(s), 1e-8f);
    }
}

// Kernel 2: out[c,p] = (W@X)[c,p] * rs[c] / max(||x_p||,1e-8), f32 out.
// EXACT round-0 champion skeleton (grid 1024, (256,3), per-kc 2 barriers,
// in-loop X loads consumed immediately — the fine-grained cross-block
// overlap that every coarser schedule lost). ONE change: A staged via
// global_load_lds from the prebuilt bf16 W image (swizzle folded into the
// per-lane SOURCE address, linear LDS dest; read formulas unchanged).
// Removes ~64 pack2 + 8 A loads + 8 A LDS-writes per thread per kc.
// NO cross-barrier register carry (R1/R2/R3 spill lesson).
__global__ __launch_bounds__(256, 3) void coshead_gemm(
    const void* __restrict__ Xg_, const u16* __restrict__ Wbf,
    const float* __restrict__ rs_ws, float* __restrict__ Og)
{
    __shared__ char smem_[32768 + 8192];
    char* sA = smem_;            // [256 rows][8 slots x 16 B]; slot s holds granule s^(row&7)
    char* sB = smem_ + 32768;    // [64 pix][8 granules x 16 B], swizzled

    const int t  = (int)threadIdx.x;
    const int l  = t & 63;
    const int w  = t >> 6;
    const int p0 = (int)blockIdx.x * 64;
    const int bf = detect_bf16_input(Xg_);

    const int g    = t & 7;      // pixel octet
    const int r    = t >> 3;     // k-pair row 0..31
    const int m16  = l & 15;
    const int quad = l >> 4;

    // sA staging map: call j covers rows j*32 + w*8 .. +7 (1 KB, lane-linear
    // dest). lane l -> row_local = l>>3, slot = l&7; source granule =
    // slot ^ (row&7) = (l&7)^(l>>3): a per-lane constant.
    const int lrow = l >> 3;
    const int gsl  = (l & 7) ^ lrow;
    const u16* wsrc = Wbf + ((size_t)(w * 8 + lrow) << 8) + gsl * 8;
    char* ldsA = sA + w * 1024;   // wave-uniform dest; +j*4096 per call

    float ssq[8];
#pragma unroll
    for (int j = 0; j < 8; ++j) ssq[j] = 0.f;
    f32x4 acc[4][4];
#pragma unroll
    for (int a = 0; a < 4; ++a)
#pragma unroll
        for (int b = 0; b < 4; ++b)
#pragma unroll
            for (int i = 0; i < 4; ++i) acc[a][b][i] = 0.f;

    for (int kc = 0; kc < 4; ++kc) {
        // ---- A: 8 x 1 KB wave-DMA from the L2-resident bf16 W image.
        // Issued first; latency drains under the B staging below, completes
        // at the leading barrier. ----
#pragma unroll
        for (int j = 0; j < 8; ++j) {
            __builtin_amdgcn_global_load_lds(
                (const __attribute__((address_space(1))) void*)(wsrc + j * 8192 + kc * 64),
                (__attribute__((address_space(3))) void*)(ldsA + j * 4096),
                16, 0, 0);
        }

        if (bf) {
            // ---- insurance path: bf16 input ----
            const u16* xp = (const u16*)Xg_ + (size_t)(2 * r + kc * 64) * P + p0 + g * 8;
            const uint4 v0 = *(const uint4*)xp;
            const uint4 v1 = *(const uint4*)(xp + P);
            const uint32_t e0[4] = {v0.x, v0.y, v0.z, v0.w};
            const uint32_t e1[4] = {v1.x, v1.y, v1.z, v1.w};
#pragma unroll
            for (int d = 0; d < 4; ++d) {
                const float f00 = bfbits2f(e0[d] & 0xFFFFu), f01 = bfbits2f(e0[d] >> 16);
                const float f10 = bfbits2f(e1[d] & 0xFFFFu), f11 = bfbits2f(e1[d] >> 16);
                ssq[2 * d]     += f00 * f00 + f10 * f10;
                ssq[2 * d + 1] += f01 * f01 + f11 * f11;
                const uint32_t d0 = (e0[d] & 0xFFFFu) | (e1[d] << 16);
                const uint32_t d1 = (e0[d] >> 16) | (e1[d] & 0xFFFF0000u);
                const int pj0 = g * 8 + 2 * d, pj1 = pj0 + 1;
                *(uint32_t*)(sB + pj0 * 128 + (((r >> 2) ^ (pj0 & 7) ^ g) * 16) + (r & 3) * 4) = d0;
                *(uint32_t*)(sB + pj1 * 128 + (((r >> 2) ^ (pj1 & 7) ^ g) * 16) + (r & 3) * 4) = d1;
            }
        } else {
            // ---- f32 path: load in-loop, consume immediately (round-0 form;
            // NO register carry across the barrier) ----
            const float* xp = (const float*)Xg_ + (size_t)(2 * r + kc * 64) * P + p0 + g * 8;
            const f32x4 c0  = *(const f32x4*)xp;
            const f32x4 c1  = *(const f32x4*)(xp + 4);
            const f32x4 d0v = *(const f32x4*)(xp + P);
            const f32x4 d1v = *(const f32x4*)(xp + P + 4);
            const float f0[8] = {c0[0], c0[1], c0[2], c0[3], c1[0], c1[1], c1[2], c1[3]};
            const float f1[8] = {d0v[0], d0v[1], d0v[2], d0v[3], d1v[0], d1v[1], d1v[2], d1v[3]};
#pragma unroll
            for (int j = 0; j < 8; ++j) {
                ssq[j] += f0[j] * f0[j] + f1[j] * f1[j];
                const int pix = g * 8 + j;
                *(uint32_t*)(sB + pix * 128 + (((r >> 2) ^ (pix & 7) ^ g) * 16) + (r & 3) * 4) =
                    pack2(f0[j], f1[j]);
            }
        }
        __syncthreads();   // sA DMA drained + sB writes visible

        // ---- MFMA: 2 K=32 steps; wave tile 64 classes x 64 pixels ----
#pragma unroll
        for (int kk = 0; kk < 2; ++kk) {
            bf16x8 af[4], bfr[4];
#pragma unroll
            for (int tm = 0; tm < 4; ++tm) {
                const int row = w * 64 + tm * 16 + m16;
                af[tm] = *(const bf16x8*)(sA + row * 128 + (((kk * 4 + quad) ^ (row & 7)) * 16));
            }
#pragma unroll
            for (int tn = 0; tn < 4; ++tn) {
                const int pix = tn * 16 + m16;
                bfr[tn] = *(const bf16x8*)(sB + pix * 128 +
                           (((kk * 4 + quad) ^ (pix & 7) ^ (pix >> 3)) * 16));
            }
#pragma unroll
            for (int tm = 0; tm < 4; ++tm)
#pragma unroll
                for (int tn = 0; tn < 4; ++tn)
                    acc[tm][tn] = __builtin_amdgcn_mfma_f32_16x16x32_bf16(
                        af[tm], bfr[tn], acc[tm][tn], 0, 0, 0);
        }
        __syncthreads();   // protects sA/sB rewrite next kc
    }

    // ---- epilogue: x-norms via LDS transpose-reduce ----
    float* xs   = (float*)sA;    // [32][64] partial ssq
    float* xinv = (float*)sB;    // [64]
#pragma unroll
    for (int j = 0; j < 8; ++j) xs[r * 64 + g * 8 + j] = ssq[j];
    __syncthreads();
    if (t < 64) {
        float sx = 0.f;
#pragma unroll
        for (int rr = 0; rr < 32; ++rr) sx += xs[rr * 64 + t];
        xinv[t] = 1.0f / fmaxf(sqrtf(sx), 1e-8f);
    }
    __syncthreads();

    // ---- scaled f32 store. class = w*64+tm*16+quad*4+i ; pixel = p0+tn*16+m16 ----
    float inv4[4];
#pragma unroll
    for (int tn = 0; tn < 4; ++tn) inv4[tn] = xinv[tn * 16 + m16];
#pragma unroll
    for (int tm = 0; tm < 4; ++tm) {
        const int cbase = w * 64 + tm * 16 + quad * 4;
        const f32x4 rs4 = *(const f32x4*)(rs_ws + cbase);
#pragma unroll
        for (int tn = 0; tn < 4; ++tn) {
#pragma unroll
            for (int i = 0; i < 4; ++i) {
                Og[(size_t)(cbase + i) * P + p0 + tn * 16 + m16] =
                    acc[tm][tn][i] * rs4[i] * inv4[tn];
            }
        }
    }
}

extern "C" void kernel_launch(void* const* d_in, const int* in_sizes, int n_in,
                              void* d_out, int out_size, void* d_ws, size_t ws_size,
                              hipStream_t stream) {
    (void)out_size; (void)ws_size;
    const void* X = d_in[0];
    const void* W = d_in[1];
    const void* S = d_in[2];
    for (int i = 0; i < n_in; ++i) {
        if (in_sizes[i] == 256 * 65536) X = d_in[i];
        else if (in_sizes[i] == 256 * 256) W = d_in[i];
        else if (in_sizes[i] == 256)      S = d_in[i];
    }
    float* rs  = (float*)d_ws;
    u16*   wbf = (u16*)((char*)d_ws + 1024);   // 128 KB bf16 W image
    coshead_prep<<<dim3(256), dim3(64), 0, stream>>>(X, W, S, rs, wbf);
    coshead_gemm<<<dim3(1024), dim3(256), 0, stream>>>(X, wbf, rs, (float*)d_out);
}